// Round 2
// baseline (122.201 us; speedup 1.0000x reference)
//
#include <hip/hip_runtime.h>

// BlockLinear: y[r, c*3+o] = sum_i x[r, c*3+i] * W[c*9 + o*3 + i] + b[c*3+o]
// B=16384 rows, IN_FEATURES=3072, C=1024 components (3x3 Linear each).
//
// Memory-bound streaming: 402 MB total, copy ceiling ~6.3 TB/s -> ~64 us floor.
// Round-2 structure: each thread owns a QUAD of 4 consecutive components
// (12 floats = 48 B = 3 float4) so ALL global traffic is 16 B/lane dwordx4,
// vs round-1's 12 B/lane dwordx3 (75% per-instruction VMEM efficiency).

#define NROWS      16384
#define INF        3072
#define NQUAD      256     // 1024 components / 4 per thread
#define ROWS_PER_T 8

__global__ __launch_bounds__(256)
void block_linear_kernel(const float* __restrict__ x,
                         const float* __restrict__ W,
                         const float* __restrict__ bias,
                         float* __restrict__ out) {
    const int tid = blockIdx.x * blockDim.x + threadIdx.x;
    const int q   = tid & (NQUAD - 1);   // quad index; consecutive lanes -> consecutive quads
    const int rg  = tid >> 8;            // row group

    // ---- Load 4 components' weights (36 floats = 9 float4) and biases
    //      (12 floats = 3 float4) into registers; static indices only. ----
    float wq[36];
    {
        const float4* W4 = reinterpret_cast<const float4*>(W) + (size_t)q * 9;
        #pragma unroll
        for (int j = 0; j < 9; ++j) {
            float4 t = W4[j];
            wq[4*j+0] = t.x; wq[4*j+1] = t.y; wq[4*j+2] = t.z; wq[4*j+3] = t.w;
        }
    }
    float bq[12];
    {
        const float4* B4 = reinterpret_cast<const float4*>(bias) + (size_t)q * 3;
        #pragma unroll
        for (int j = 0; j < 3; ++j) {
            float4 t = B4[j];
            bq[4*j+0] = t.x; bq[4*j+1] = t.y; bq[4*j+2] = t.z; bq[4*j+3] = t.w;
        }
    }

    const float4* x4   = reinterpret_cast<const float4*>(x);
    float4*       out4 = reinterpret_cast<float4*>(out);
    const int r0 = rg * ROWS_PER_T;

    #pragma unroll
    for (int k = 0; k < ROWS_PER_T; ++k) {
        const size_t base = (size_t)(r0 + k) * (INF / 4) + (size_t)q * 3;
        float4 v0 = x4[base + 0];
        float4 v1 = x4[base + 1];
        float4 v2 = x4[base + 2];

        float xin[12] = { v0.x, v0.y, v0.z, v0.w,
                          v1.x, v1.y, v1.z, v1.w,
                          v2.x, v2.y, v2.z, v2.w };
        float yo[12];
        #pragma unroll
        for (int c = 0; c < 4; ++c) {
            const float i0 = xin[c*3+0], i1 = xin[c*3+1], i2 = xin[c*3+2];
            #pragma unroll
            for (int o = 0; o < 3; ++o) {
                yo[c*3+o] = fmaf(wq[c*9+o*3+0], i0,
                            fmaf(wq[c*9+o*3+1], i1,
                            fmaf(wq[c*9+o*3+2], i2, bq[c*3+o])));
            }
        }

        float4 y0 = { yo[0], yo[1], yo[2],  yo[3]  };
        float4 y1 = { yo[4], yo[5], yo[6],  yo[7]  };
        float4 y2 = { yo[8], yo[9], yo[10], yo[11] };
        out4[base + 0] = y0;
        out4[base + 1] = y1;
        out4[base + 2] = y2;
    }
}

extern "C" void kernel_launch(void* const* d_in, const int* in_sizes, int n_in,
                              void* d_out, int out_size, void* d_ws, size_t ws_size,
                              hipStream_t stream) {
    const float* x = (const float*)d_in[0];
    const float* W = (const float*)d_in[1];
    const float* b = (const float*)d_in[2];
    float* out = (float*)d_out;

    const int total_threads = NQUAD * (NROWS / ROWS_PER_T);  // 524,288
    const int block = 256;
    const int grid = total_threads / block;                  // 2048
    block_linear_kernel<<<grid, block, 0, stream>>>(x, W, b, out);
}

// Round 3
// 93.516 us; speedup vs baseline: 1.3067x; 1.3067x over previous
//
#include <hip/hip_runtime.h>

// BlockLinear: y[r, c*3+o] = sum_i x[r, c*3+i] * W[c*9 + o*3 + i] + b[c*3+o]
// B=16384 rows, IN_FEATURES=3072 (=768 float4), C=1024 components (3x3 each).
//
// Memory-bound streaming: 402 MB total, copy ceiling ~6.3 TB/s -> ~64 us floor.
// Round-3 structure: LDS-staged repack.
//   - Global loads/stores: contiguous wave float4 (lane i <-> float4 i),
//     identical pattern to a peak-BW D2D copy. (Round 2's 48B-stride dwordx4
//     broke wave contiguity -> 2.4 TB/s. Round 1's dwordx3 was contiguous but
//     12B/lane -> 5.4 TB/s.)
//   - Repack 4x3-float components per thread through LDS. ds_read_b128 at
//     byte 48*t: start-dword 12t mod 32 covers {0,12,24,4,16,28,8,20} per
//     8 lanes -> all 32 banks, conflict-free.
// One block = one row; each block processes 8 rows; 2 barriers/row.

#define NROWS      16384
#define INF4       768     // float4s per row
#define ROWS_PER_B 8

__global__ __launch_bounds__(256)
void block_linear_kernel(const float* __restrict__ x,
                         const float* __restrict__ W,
                         const float* __restrict__ bias,
                         float* __restrict__ out) {
    __shared__ float4 sin_[INF4];   // 12 KB
    __shared__ float4 sout[INF4];   // 12 KB
    const int tid = threadIdx.x;

    // Thread t owns quad q = t (components 4t..4t+3) for EVERY row.
    // 36 weights + 12 biases in registers, loaded once.
    float wq[36];
    {
        const float4* W4 = reinterpret_cast<const float4*>(W) + (size_t)tid * 9;
        #pragma unroll
        for (int j = 0; j < 9; ++j) {
            float4 t = W4[j];
            wq[4*j+0] = t.x; wq[4*j+1] = t.y; wq[4*j+2] = t.z; wq[4*j+3] = t.w;
        }
    }
    float bq[12];
    {
        const float4* B4 = reinterpret_cast<const float4*>(bias) + (size_t)tid * 3;
        #pragma unroll
        for (int j = 0; j < 3; ++j) {
            float4 t = B4[j];
            bq[4*j+0] = t.x; bq[4*j+1] = t.y; bq[4*j+2] = t.z; bq[4*j+3] = t.w;
        }
    }

    const float4* x4   = reinterpret_cast<const float4*>(x);
    float4*       out4 = reinterpret_cast<float4*>(out);

    for (int k = 0; k < ROWS_PER_B; ++k) {
        const size_t rowbase = ((size_t)blockIdx.x * ROWS_PER_B + k) * INF4;

        // ---- stage in: contiguous wave float4 loads ----
        #pragma unroll
        for (int p = 0; p < 3; ++p)
            sin_[tid + 256 * p] = x4[rowbase + tid + 256 * p];
        __syncthreads();

        // ---- repack + compute: thread t reads its 12 floats ----
        float4 v0 = sin_[tid * 3 + 0];
        float4 v1 = sin_[tid * 3 + 1];
        float4 v2 = sin_[tid * 3 + 2];
        float xin[12] = { v0.x, v0.y, v0.z, v0.w,
                          v1.x, v1.y, v1.z, v1.w,
                          v2.x, v2.y, v2.z, v2.w };
        float yo[12];
        #pragma unroll
        for (int c = 0; c < 4; ++c) {
            const float i0 = xin[c*3+0], i1 = xin[c*3+1], i2 = xin[c*3+2];
            #pragma unroll
            for (int o = 0; o < 3; ++o) {
                yo[c*3+o] = fmaf(wq[c*9+o*3+0], i0,
                            fmaf(wq[c*9+o*3+1], i1,
                            fmaf(wq[c*9+o*3+2], i2, bq[c*3+o])));
            }
        }
        float4 y0 = { yo[0], yo[1], yo[2],  yo[3]  };
        float4 y1 = { yo[4], yo[5], yo[6],  yo[7]  };
        float4 y2 = { yo[8], yo[9], yo[10], yo[11] };
        sout[tid * 3 + 0] = y0;
        sout[tid * 3 + 1] = y1;
        sout[tid * 3 + 2] = y2;
        __syncthreads();

        // ---- stage out: contiguous wave float4 stores ----
        #pragma unroll
        for (int p = 0; p < 3; ++p)
            out4[rowbase + tid + 256 * p] = sout[tid + 256 * p];
        // Next iteration's stage-in overwrite of sin_ is safe: every thread
        // passed the compute->store barrier (sin_ reads done), and the next
        // __syncthreads() orders sout reuse.
    }
}

extern "C" void kernel_launch(void* const* d_in, const int* in_sizes, int n_in,
                              void* d_out, int out_size, void* d_ws, size_t ws_size,
                              hipStream_t stream) {
    const float* x = (const float*)d_in[0];
    const float* W = (const float*)d_in[1];
    const float* b = (const float*)d_in[2];
    float* out = (float*)d_out;

    const int block = 256;
    const int grid  = NROWS / ROWS_PER_B;   // 2048 blocks
    block_linear_kernel<<<grid, block, 0, stream>>>(x, W, b, out);
}

// Round 4
// 86.797 us; speedup vs baseline: 1.4079x; 1.0774x over previous
//
#include <hip/hip_runtime.h>

// BlockLinear: y[r, c*3+o] = sum_i x[r, c*3+i] * W[c*9 + o*3 + i] + b[c*3+o]
// B=16384 rows, IN_FEATURES=3072 (=768 float4), C=1024 components (3x3 each).
//
// Memory-bound streaming: 402 MB total, copy ceiling ~6.3 TB/s -> ~64 us floor.
//
// Round-4 structure: WAVE-LOCAL LDS repack, zero __syncthreads.
//   - A wave owns a quarter-row chunk: 64 lanes x 3 contiguous float4
//     (lane <-> float4, at +0/+64/+128) = 768 dwords = exactly 256 components.
//     Global loads AND stores are copy-pattern contiguous.
//   - Repack through a wave-private 3KB LDS buffer. Cross-lane ordering within
//     one wave needs only s_waitcnt lgkmcnt(0) (same-wave LDS ops process in
//     order) -- no block barriers, so waves run fully decoupled and HBM
//     latency hides behind occupancy (round 3 failed on barrier lockstep).
//   - Swizzled ds_read/write_b128 at byte 48*lane: 2-way bank aliasing only
//     (free per m136).
//   - col (quarter index) is fixed per wave across its 8 rows -> 48 weight
//     floats load once into registers, L2-resident.

#define NROWS 16384
#define INF4  768          // float4 per row
#define QTR   192          // float4 per quarter-row chunk

__global__ __launch_bounds__(256)
void block_linear_kernel(const float* __restrict__ x,
                         const float* __restrict__ W,
                         const float* __restrict__ bias,
                         float* __restrict__ out) {
    __shared__ float4 sbuf[4][QTR];          // 3KB per wave, wave-private
    const int tid = threadIdx.x;
    const int l   = tid & 63;                // lane
    const int wb  = tid >> 6;                // wave within block
    const int gw  = blockIdx.x * 4 + wb;     // global wave id, 0..8191
    const int col = gw & 3;                  // quarter-row index (fixed)
    const int r0  = gw >> 2;                 // first row, 0..2047

    // ---- weights for this lane's 4 components (quad q), loaded once ----
    const int q = col * 64 + l;              // quad index 0..255
    float wq[36];
    {
        const float4* W4 = reinterpret_cast<const float4*>(W) + (size_t)q * 9;
        #pragma unroll
        for (int j = 0; j < 9; ++j) {
            float4 t = W4[j];
            wq[4*j+0] = t.x; wq[4*j+1] = t.y; wq[4*j+2] = t.z; wq[4*j+3] = t.w;
        }
    }
    float bq[12];
    {
        const float4* B4 = reinterpret_cast<const float4*>(bias) + (size_t)q * 3;
        #pragma unroll
        for (int j = 0; j < 3; ++j) {
            float4 t = B4[j];
            bq[4*j+0] = t.x; bq[4*j+1] = t.y; bq[4*j+2] = t.z; bq[4*j+3] = t.w;
        }
    }

    const float4* x4   = reinterpret_cast<const float4*>(x);
    float4*       out4 = reinterpret_cast<float4*>(out);
    float4*       sb   = sbuf[wb];

    #pragma unroll 2
    for (int k = 0; k < 8; ++k) {
        const int row = r0 + 2048 * k;
        const size_t base = (size_t)row * INF4 + (size_t)col * QTR;

        // 1) copy-pattern global loads (lane <-> float4)
        float4 v0 = x4[base + l];
        float4 v1 = x4[base + l + 64];
        float4 v2 = x4[base + l + 128];

        // 2) contiguous LDS write
        sb[l]       = v0;
        sb[l + 64]  = v1;
        sb[l + 128] = v2;
        asm volatile("s_waitcnt lgkmcnt(0)" ::: "memory");

        // 3) swizzled LDS read: lane's 4 components = float4s 3l..3l+2
        float4 a0 = sb[3*l + 0];
        float4 a1 = sb[3*l + 1];
        float4 a2 = sb[3*l + 2];
        float xin[12] = { a0.x, a0.y, a0.z, a0.w,
                          a1.x, a1.y, a1.z, a1.w,
                          a2.x, a2.y, a2.z, a2.w };
        float yo[12];
        #pragma unroll
        for (int c = 0; c < 4; ++c) {
            const float i0 = xin[c*3+0], i1 = xin[c*3+1], i2 = xin[c*3+2];
            #pragma unroll
            for (int o = 0; o < 3; ++o) {
                yo[c*3+o] = fmaf(wq[c*9+o*3+0], i0,
                            fmaf(wq[c*9+o*3+1], i1,
                            fmaf(wq[c*9+o*3+2], i2, bq[c*3+o])));
            }
        }

        // 4) swizzled LDS write-back (same addresses this lane just read)
        float4 y0 = { yo[0], yo[1], yo[2],  yo[3]  };
        float4 y1 = { yo[4], yo[5], yo[6],  yo[7]  };
        float4 y2 = { yo[8], yo[9], yo[10], yo[11] };
        sb[3*l + 0] = y0;
        sb[3*l + 1] = y1;
        sb[3*l + 2] = y2;
        asm volatile("s_waitcnt lgkmcnt(0)" ::: "memory");

        // 5) contiguous LDS read -> copy-pattern global stores
        out4[base + l]       = sb[l];
        out4[base + l + 64]  = sb[l + 64];
        out4[base + l + 128] = sb[l + 128];
        // Next iteration's step-2 writes to the same LDS addrs are safe:
        // same-wave DS ops process in order, so step-5 reads complete first.
    }
}

extern "C" void kernel_launch(void* const* d_in, const int* in_sizes, int n_in,
                              void* d_out, int out_size, void* d_ws, size_t ws_size,
                              hipStream_t stream) {
    const float* x = (const float*)d_in[0];
    const float* W = (const float*)d_in[1];
    const float* b = (const float*)d_in[2];
    float* out = (float*)d_out;

    const int block = 256;                 // 4 waves
    const int grid  = 2048;                // 8192 waves; 8 quarter-row chunks each
    block_linear_kernel<<<grid, block, 0, stream>>>(x, W, b, out);
}